// Round 3
// baseline (274.336 us; speedup 1.0000x reference)
//
#include <hip/hip_runtime.h>

#define NN 8192
#define HH 64
constexpr float LALPHA = 0.2f;

typedef __attribute__((ext_vector_type(8))) short bf16x8;
typedef __attribute__((ext_vector_type(4))) float f32x4;

__device__ inline short f2bf(float f) {
  unsigned u = __builtin_bit_cast(unsigned, f);
  u += 0x7FFFu + ((u >> 16) & 1u);
  return (short)(u >> 16);
}

// ---------------------------------------------------------------- diag extract
__global__ __launch_bounds__(256) void k_diag(const float* __restrict__ na,
                                              const float* __restrict__ ea,
                                              float* __restrict__ dn,
                                              float* __restrict__ de) {
  int i = blockIdx.x * 256 + threadIdx.x;
  if (i < NN) {
    dn[i] = na[(size_t)i * NN + i];
    de[i] = ea[(size_t)i * NN + i];
  }
}

// ---------------------------------------------------------------- column sums of h
__global__ __launch_bounds__(256) void k_hbarP(const float* __restrict__ h,
                                               float* __restrict__ HbP) {
  int c = threadIdx.x & 63, rs = threadIdx.x >> 6;
  int r0 = blockIdx.x * 128;
  float s = 0.f;
  for (int r = rs; r < 128; r += 4) s += h[(size_t)(r0 + r) * HH + c];
  __shared__ float red[4][64];
  red[rs][c] = s;
  __syncthreads();
  if (rs == 0) HbP[blockIdx.x * 64 + c] = red[0][c] + red[1][c] + red[2][c] + red[3][c];
}

__global__ __launch_bounds__(64) void k_hbarF(const float* __restrict__ HbP,
                                              float* __restrict__ Hb) {
  int c = threadIdx.x;
  float s = 0.f;
  for (int b = 0; b < 64; ++b) s += HbP[b * 64 + c];
  Hb[c] = s;
}

// ---------------------------------------------------------------- h -> ht (transposed bf16 [64][NN])
__global__ __launch_bounds__(256) void k_ht(const float* __restrict__ h,
                                            unsigned short* __restrict__ ht) {
  __shared__ float tile[64][65];
  int j0 = blockIdx.x * 64;
  for (int l = threadIdx.x; l < 64 * 64; l += 256) {
    int r = l >> 6, c = l & 63;
    tile[r][c] = h[(size_t)(j0 + r) * HH + c];
  }
  __syncthreads();
  for (int l = threadIdx.x; l < 64 * 64; l += 256) {
    int c = l >> 6, r = l & 63;
    ht[(size_t)c * NN + j0 + r] = (unsigned short)f2bf(tile[r][c]);
  }
}

// ---------------------------------------------------------------- heavy masked matmuls via MFMA
// Sp_raw = (na>0)@h, Tf_raw = ea@h, Tp_raw = relu(ea)@h, cp_raw = #(ea>0) per row
// mfma_f32_16x16x32_bf16: A[l&15][8*(l>>4)+j], B[8*(l>>4)+j][l&15], D[(l>>4)*4+r][l&15]
// Prefetch-1 on the HBM streams; 4 waves/SIMD via KS-way k-split.
template <int KS>
__global__ __launch_bounds__(256, 4) void k_stageA(
    const float* __restrict__ na, const float* __restrict__ ea,
    const unsigned short* __restrict__ ht,
    float* __restrict__ SpP, float* __restrict__ TfP,
    float* __restrict__ TpP, float* __restrict__ cpP) {
  const int lane  = threadIdx.x & 63;
  const int wid   = threadIdx.x >> 6;
  const int row16 = lane & 15;
  const int kgrp  = lane >> 4;
  const int i0    = blockIdx.x * 64 + wid * 16;
  const int ks    = blockIdx.y;
  const int kbeg  = ks * (NN / KS);
  const int kend  = kbeg + NN / KS;

  f32x4 accS[4] = {}, accF[4] = {}, accP[4] = {};
  float cnt = 0.f;

  const float* naRow = na + (size_t)(i0 + row16) * NN;
  const float* eaRow = ea + (size_t)(i0 + row16) * NN;

  // prologue: load first chunk
  int kk = kbeg + kgrp * 8;
  float4 A0 = *reinterpret_cast<const float4*>(naRow + kk);
  float4 A1 = *reinterpret_cast<const float4*>(naRow + kk + 4);
  float4 E0 = *reinterpret_cast<const float4*>(eaRow + kk);
  float4 E1 = *reinterpret_cast<const float4*>(eaRow + kk + 4);

  for (int k0 = kbeg; k0 < kend; k0 += 32) {
    // issue next-iteration HBM loads early (prefetch depth 1)
    const int kn  = (k0 + 32 < kend) ? k0 + 32 : kbeg;
    const int kkn = kn + kgrp * 8;
    const float4 A0n = *reinterpret_cast<const float4*>(naRow + kkn);
    const float4 A1n = *reinterpret_cast<const float4*>(naRow + kkn + 4);
    const float4 E0n = *reinterpret_cast<const float4*>(eaRow + kkn);
    const float4 E1n = *reinterpret_cast<const float4*>(eaRow + kkn + 4);

    const int kc = k0 + kgrp * 8;
    const float av[8] = {A0.x, A0.y, A0.z, A0.w, A1.x, A1.y, A1.z, A1.w};
    const float ev[8] = {E0.x, E0.y, E0.z, E0.w, E1.x, E1.y, E1.z, E1.w};
    bf16x8 fS, fF, fP;
#pragma unroll
    for (int q = 0; q < 8; ++q) {
      fS[q] = (av[q] > 0.f) ? (short)0x3F80 : (short)0;
      fF[q] = f2bf(ev[q]);
      fP[q] = f2bf(fmaxf(ev[q], 0.f));
      cnt += (ev[q] > 0.f) ? 1.f : 0.f;
    }
#pragma unroll
    for (int c = 0; c < 4; ++c) {
      const bf16x8 fB = *reinterpret_cast<const bf16x8*>(
          ht + (size_t)(c * 16 + row16) * NN + kc);
      accS[c] = __builtin_amdgcn_mfma_f32_16x16x32_bf16(fS, fB, accS[c], 0, 0, 0);
      accF[c] = __builtin_amdgcn_mfma_f32_16x16x32_bf16(fF, fB, accF[c], 0, 0, 0);
      accP[c] = __builtin_amdgcn_mfma_f32_16x16x32_bf16(fP, fB, accP[c], 0, 0, 0);
    }
    A0 = A0n; A1 = A1n; E0 = E0n; E1 = E1n;
  }
  cnt += __shfl_xor(cnt, 16);
  cnt += __shfl_xor(cnt, 32);
  if (lane < 16) cpP[ks * NN + i0 + lane] = cnt;

  const size_t base = (size_t)ks * ((size_t)NN * HH);
#pragma unroll
  for (int c = 0; c < 4; ++c) {
#pragma unroll
    for (int r = 0; r < 4; ++r) {
      const int row = i0 + kgrp * 4 + r;
      const int col = c * 16 + row16;
      const size_t idx = base + (size_t)row * HH + col;
      SpP[idx] = accS[c][r];
      TfP[idx] = accF[c][r];
      TpP[idx] = accP[c][r];
    }
  }
}

// ---------------------------------------------------------------- combine partials
template <int KS>
__global__ __launch_bounds__(256) void k_combine(
    const float* __restrict__ h, const float* __restrict__ dn,
    const float* __restrict__ de, const float* __restrict__ Hb,
    float* __restrict__ SpP, float* __restrict__ TfP,
    float* __restrict__ TpP, const float* __restrict__ cpP,
    float* __restrict__ cpF) {
  const int SZ = NN * HH;
  int idx = blockIdx.x * 256 + threadIdx.x;
  int i = idx >> 6, c = idx & 63;
  float hic = h[idx];
  float dni = dn[i], dei = de[i];
  float sp = 0.f, tf = 0.f, tp = 0.f;
#pragma unroll
  for (int s = 0; s < KS; ++s) {
    sp += SpP[(size_t)s * SZ + idx];
    tf += TfP[(size_t)s * SZ + idx];
    tp += TpP[(size_t)s * SZ + idx];
  }
  // remove diagonal contributions (A = adj - diag)
  sp -= (dni > 0.f) ? hic : 0.f;
  tf -= dei * hic;
  tp -= fmaxf(dei, 0.f) * hic;
  // finals alias onto partial buffers (same-thread read-before-write only)
  SpP[idx] = sp;                       // Sp
  SpP[SZ + idx] = Hb[c] - hic - sp;    // Sm
  TpP[idx] = tp;                       // Tp
  TpP[SZ + idx] = tf - tp;             // Tm
  if (idx < NN) {
    float cntv = 0.f;
#pragma unroll
    for (int s = 0; s < KS; ++s) cntv += cpP[s * NN + idx];
    cntv -= (de[idx] > 0.f) ? 1.f : 0.f;
    cpF[idx] = cntv;
  }
}

// ---------------------------------------------------------------- [N,64] @ [64,64]
__global__ __launch_bounds__(256) void k_mm64(const float* __restrict__ X,
                                              const float* __restrict__ W,
                                              float* __restrict__ Y) {
  __shared__ float Ws[64][64];
  __shared__ float Xs[16][64];
  const int t = threadIdx.x;
  for (int l = t; l < 4096; l += 256) Ws[l >> 6][l & 63] = W[l];
  const int i0 = blockIdx.x * 16;
  for (int l = t; l < 1024; l += 256)
    Xs[l >> 6][l & 63] = X[(size_t)(i0 + (l >> 6)) * 64 + (l & 63)];
  __syncthreads();
  const int lane = t & 63, wid = t >> 6;
  float acc[4] = {0.f, 0.f, 0.f, 0.f};
  for (int k = 0; k < 64; ++k) {
    float wv = Ws[k][lane];
#pragma unroll
    for (int r = 0; r < 4; ++r) acc[r] += Xs[wid * 4 + r][k] * wv;
  }
#pragma unroll
  for (int r = 0; r < 4; ++r) Y[(size_t)(i0 + wid * 4 + r) * 64 + lane] = acc[r];
}

// ---------------------------------------------------------------- analytic GAT softmax
__global__ __launch_bounds__(256) void k_gat(
    const float* __restrict__ HP, const float* __restrict__ HM,
    const float* __restrict__ a, const float* __restrict__ Tp,
    const float* __restrict__ Tm, const float* __restrict__ cpF,
    float* __restrict__ U) {
  const int lane = threadIdx.x & 63;
  const int i = blockIdx.x * 4 + (threadIdx.x >> 6);
  const int idx = i * 64 + lane;
  float hp = HP[idx], hm = HM[idx];
  float a0 = a[lane], a1 = a[64 + lane];
  float ep = hp * a0 + hm * a1;
  float em = hm * a0 + hp * a1;
#pragma unroll
  for (int off = 32; off >= 1; off >>= 1) {
    ep += __shfl_xor(ep, off);
    em += __shfl_xor(em, off);
  }
  ep = ep > 0.f ? ep : LALPHA * ep;
  em = em > 0.f ? em : LALPHA * em;
  float cp = cpF[i];
  float cm = (float)(NN - 1) - cp;
  const float NEGI = -3.0e38f;
  float m = fmaxf(cp > 0.f ? ep : NEGI, cm > 0.f ? em : NEGI);
  float xp = (cp > 0.f) ? expf(ep - m) : 0.f;
  float xm = (cm > 0.f) ? expf(em - m) : 0.f;
  float denom = cp * xp + cm * xm;
  float inv = denom > 0.f ? 1.f / denom : 0.f;
  float wp = xp * inv, wm = xm * inv;
  U[idx] = wp * Tp[idx] + wm * Tm[idx];
}

// ---------------------------------------------------------------- GRU cell (r,z,n)
template <int XK>
__global__ __launch_bounds__(64) void k_gru(
    const float* __restrict__ x1, const float* __restrict__ x2,
    const float* __restrict__ wih, const float* __restrict__ whh,
    const float* __restrict__ bih, const float* __restrict__ bhh,
    const float* __restrict__ h, float* __restrict__ out) {
  const int c = threadIdx.x;
  const int i0 = blockIdx.x * 8;
  __shared__ float xs[8][XK];
  __shared__ float hs[8][64];
  for (int l = c; l < 8 * XK; l += 64) {
    int r = l / XK, k = l % XK;
    float v;
    if (XK == 128)
      v = (k < 64) ? x1[(size_t)(i0 + r) * 64 + k]
                   : x2[(size_t)(i0 + r) * 64 + (k - 64)];
    else
      v = x1[(size_t)(i0 + r) * 64 + k];
    xs[r][k] = v;
  }
  for (int l = c; l < 8 * 64; l += 64) {
    int r = l >> 6, k = l & 63;
    hs[r][k] = h[(size_t)(i0 + r) * 64 + k];
  }
  __syncthreads();
  float gr[8] = {}, gz[8] = {}, gn[8] = {};
  for (int k = 0; k < XK; ++k) {
    float wr = wih[(size_t)c * XK + k];
    float wz = wih[(size_t)(64 + c) * XK + k];
    float wn = wih[(size_t)(128 + c) * XK + k];
#pragma unroll
    for (int r = 0; r < 8; ++r) {
      float xv = xs[r][k];
      gr[r] += xv * wr; gz[r] += xv * wz; gn[r] += xv * wn;
    }
  }
  float hr[8] = {}, hz[8] = {}, hn[8] = {};
  for (int k = 0; k < 64; ++k) {
    float ur = whh[(size_t)c * 64 + k];
    float uz = whh[(size_t)(64 + c) * 64 + k];
    float un = whh[(size_t)(128 + c) * 64 + k];
#pragma unroll
    for (int r = 0; r < 8; ++r) {
      float hv = hs[r][k];
      hr[r] += hv * ur; hz[r] += hv * uz; hn[r] += hv * un;
    }
  }
  float br = bih[c], bz = bih[64 + c], bn = bih[128 + c];
  float dr = bhh[c], dz = bhh[64 + c], dnb = bhh[128 + c];
#pragma unroll
  for (int r = 0; r < 8; ++r) {
    float rg = 1.f / (1.f + expf(-(gr[r] + br + hr[r] + dr)));
    float zg = 1.f / (1.f + expf(-(gz[r] + bz + hz[r] + dz)));
    float ng = tanhf(gn[r] + bn + rg * (hn[r] + dnb));
    out[(size_t)(i0 + r) * 64 + c] = (1.f - zg) * ng + zg * hs[r][c];
  }
}

// ---------------------------------------------------------------- final combine
__global__ __launch_bounds__(256) void k_final(const float* __restrict__ dn,
                                               const float* __restrict__ de,
                                               const float* __restrict__ EO,
                                               const float* __restrict__ NO,
                                               float* __restrict__ out) {
  int idx = blockIdx.x * 256 + threadIdx.x;
  int i = idx >> 6;
  out[idx] = de[i] * EO[idx] + dn[i] * NO[idx];
}

extern "C" void kernel_launch(void* const* d_in, const int* in_sizes, int n_in,
                              void* d_out, int out_size, void* d_ws, size_t ws_size,
                              hipStream_t stream) {
  const float* h    = (const float*)d_in[0];
  const float* na   = (const float*)d_in[1];
  const float* ea   = (const float*)d_in[2];
  const float* Wg   = (const float*)d_in[3];
  const float* ag   = (const float*)d_in[4];
  const float* wihe = (const float*)d_in[5];
  const float* whhe = (const float*)d_in[6];
  const float* bihe = (const float*)d_in[7];
  const float* bhhe = (const float*)d_in[8];
  const float* wihn = (const float*)d_in[9];
  const float* whhn = (const float*)d_in[10];
  const float* bihn = (const float*)d_in[11];
  const float* bhhn = (const float*)d_in[12];
  float* out = (float*)d_out;
  float* ws  = (float*)d_ws;

  const size_t SZ = (size_t)NN * HH;
  // choose k-split by available workspace (KS=8 needs ~52 MB)
  const size_t need8 = (24 * SZ + 16 * NN + 4160 + 64) * 4 + (size_t)NN * HH * 2;
  const int KS = (ws_size >= need8) ? 8 : 4;

  float* SpP = ws;                     // KS*SZ partials; finals: Sp=+0, Sm=+SZ
  float* TfP = ws + (size_t)KS * SZ;   // KS*SZ partials; finals: HP,HM,U,ES
  float* TpP = ws + (size_t)2 * KS * SZ; // KS*SZ partials; finals: Tp,Tm,EO,NO
  float* Sp = SpP;
  float* Sm = SpP + SZ;
  float* HP = TfP;
  float* HM = TfP + SZ;
  float* U  = TfP + 2 * SZ;
  float* ES = TfP + 3 * SZ;
  float* Tp = TpP;
  float* Tm = TpP + SZ;
  float* EO = TpP + 2 * SZ;
  float* NO = TpP + 3 * SZ;
  float* small = ws + (size_t)3 * KS * SZ;
  float* cpP = small;                  // KS*NN
  float* cpF = cpP + (size_t)KS * NN;  // NN
  float* dn  = cpF + NN;               // NN
  float* de  = dn + NN;                // NN
  float* HbP = de + NN;                // 4096
  float* Hb  = HbP + 4096;             // 64
  unsigned short* ht = (unsigned short*)(Hb + 64);  // 64*NN bf16

  k_diag<<<32, 256, 0, stream>>>(na, ea, dn, de);
  k_hbarP<<<64, 256, 0, stream>>>(h, HbP);
  k_hbarF<<<1, 64, 0, stream>>>(HbP, Hb);
  k_ht<<<NN / 64, 256, 0, stream>>>(h, ht);
  if (KS == 8) {
    k_stageA<8><<<dim3(NN / 64, 8), 256, 0, stream>>>(na, ea, ht, SpP, TfP, TpP, cpP);
    k_combine<8><<<(int)(SZ / 256), 256, 0, stream>>>(h, dn, de, Hb, SpP, TfP, TpP, cpP, cpF);
  } else {
    k_stageA<4><<<dim3(NN / 64, 4), 256, 0, stream>>>(na, ea, ht, SpP, TfP, TpP, cpP);
    k_combine<4><<<(int)(SZ / 256), 256, 0, stream>>>(h, dn, de, Hb, SpP, TfP, TpP, cpP, cpF);
  }
  k_mm64<<<NN / 16, 256, 0, stream>>>(Sp, Wg, HP);
  k_mm64<<<NN / 16, 256, 0, stream>>>(Sm, Wg, HM);
  k_gat<<<NN / 4, 256, 0, stream>>>(HP, HM, ag, Tp, Tm, cpF, U);
  k_mm64<<<NN / 16, 256, 0, stream>>>(U, Wg, ES);
  k_gru<128><<<NN / 8, 64, 0, stream>>>(Sp, Sm, wihe, whhe, bihe, bhhe, h, EO);
  k_gru<64><<<NN / 8, 64, 0, stream>>>(ES, nullptr, wihn, whhn, bihn, bhhn, h, NO);
  k_final<<<(int)(SZ / 256), 256, 0, stream>>>(dn, de, EO, NO, out);
}